// Round 4
// baseline (603.929 us; speedup 1.0000x reference)
//
#include <hip/hip_runtime.h>

#define DD 160
#define HH 160
#define WW 160
#define PL (HH*WW)       // one z-plane = 25600 voxels
#define S (DD*PL)        // 4,096,000 voxels

__device__ __forceinline__ float fmul(float a, float b){ return __fmul_rn(a,b); }
__device__ __forceinline__ float fadd(float a, float b){ return __fadd_rn(a,b); }
__device__ __forceinline__ float fsub(float a, float b){ return __fsub_rn(a,b); }

// ddf0 = (dvf0*(1-w) + dvf1*w) / 32  -- bit-exact replica of reference order
__global__ __launch_bounds__(256) void init_kernel(const float* __restrict__ dvf0,
                                                   const float* __restrict__ dvf1,
                                                   const float* __restrict__ wp,
                                                   float* __restrict__ out) {
    int i = (blockIdx.x * 256 + threadIdx.x) * 4;   // 12000 blocks cover 3S exactly
    float w = wp[0];
    float onew = fsub(1.0f, w);
    float a[4], b[4], o[4];
    *(float4*)a = *(const float4*)(dvf0 + i);
    *(float4*)b = *(const float4*)(dvf1 + i);
    #pragma unroll
    for (int j = 0; j < 4; ++j)
        o[j] = fmul(fadd(fmul(a[j], onew), fmul(b[j], w)), 0.03125f);
    *(float4*)(out + i) = *(float4*)o;
}

// out = in + trilinear_warp(in, in). Planar layout; wave footprint 32x2 in-plane;
// 4 voxels/thread along z -> 4 independent gather chains (4x MLP) + L1 plane reuse.
// Grid: 5(x) * 20(y) * 40(z-quads) = 4000 blocks; swizzle -> 20-plane slab per XCD.
__global__ __launch_bounds__(256) void warp_step(const float* __restrict__ in,
                                                 float* __restrict__ out) {
    int b  = (blockIdx.x & 7) * 500 + (blockIdx.x >> 3);
    int ix = b % 5;
    int r  = b / 5;
    int iy = r % 20;
    int iz = r / 20;                 // 0..39
    int lane = threadIdx.x & 63, wid = threadIdx.x >> 6;
    int x  = (ix << 5) | (lane & 31);
    int y  = (iy << 3) | (wid << 1) | (lane >> 5);
    int z0 = iz << 2;
    int p0 = (z0 * HH + y) * WW + x;

    // dense center loads for all 4 voxels first (independent of gathers)
    float vd[4], vh[4], vw[4];
    #pragma unroll
    for (int j = 0; j < 4; ++j) {
        vd[j] = in[p0 + j * PL];
        vh[j] = in[S + p0 + j * PL];
        vw[j] = in[2 * S + p0 + j * PL];
    }

    #pragma unroll
    for (int j = 0; j < 4; ++j) {
        int z = z0 + j;
        int p = p0 + j * PL;
        float cd = fadd((float)z, vd[j]);
        float ch = fadd((float)y, vh[j]);
        float cw = fadd((float)x, vw[j]);

        float d0 = floorf(cd), h0 = floorf(ch), w0 = floorf(cw);
        float fd = fsub(cd, d0), fh = fsub(ch, h0), fw = fsub(cw, w0);
        float gd = fsub(1.0f, fd), gh = fsub(1.0f, fh), gw = fsub(1.0f, fw);
        int d0i = (int)d0, h0i = (int)h0, w0i = (int)w0;

        float acc0 = 0.0f, acc1 = 0.0f, acc2 = 0.0f;
        #pragma unroll
        for (int dd = 0; dd < 2; ++dd) {
            #pragma unroll
            for (int dh = 0; dh < 2; ++dh) {
                #pragma unroll
                for (int dw = 0; dw < 2; ++dw) {
                    int di = d0i + dd, hi = h0i + dh, wi = w0i + dw;
                    bool valid = (di >= 0) & (di < DD) & (hi >= 0) & (hi < HH)
                               & (wi >= 0) & (wi < WW);
                    float wgt = fmul(fmul(dd ? fd : gd, dh ? fh : gh), dw ? fw : gw);
                    wgt = valid ? wgt : 0.0f;      // single select; 0*v == ref's v*0
                    int dc = min(max(di, 0), DD - 1);
                    int hc = min(max(hi, 0), HH - 1);
                    int wc = min(max(wi, 0), WW - 1);
                    int q = (dc * HH + hc) * WW + wc;
                    acc0 = fadd(acc0, fmul(in[q],         wgt));
                    acc1 = fadd(acc1, fmul(in[S + q],     wgt));
                    acc2 = fadd(acc2, fmul(in[2 * S + q], wgt));
                }
            }
        }
        out[p]         = fadd(vd[j], acc0);
        out[S + p]     = fadd(vh[j], acc1);
        out[2 * S + p] = fadd(vw[j], acc2);
    }
}

// img trilinear + cav/cor nearest warp with final (planar) ddf. 2 voxels/thread (z).
// Grid: 5 * 20 * 80 = 8000 blocks; same slab swizzle (20 planes per XCD).
__global__ __launch_bounds__(256) void final_kernel(const float* __restrict__ ddf,
                                                    const float* __restrict__ image,
                                                    const int* __restrict__ cav,
                                                    const int* __restrict__ cor,
                                                    float* __restrict__ out) {
    int b  = (blockIdx.x & 7) * 1000 + (blockIdx.x >> 3);
    int ix = b % 5;
    int r  = b / 5;
    int iy = r % 20;
    int iz = r / 20;                 // 0..79
    int lane = threadIdx.x & 63, wid = threadIdx.x >> 6;
    int x  = (ix << 5) | (lane & 31);
    int y  = (iy << 3) | (wid << 1) | (lane >> 5);
    int z0 = iz << 1;
    int p0 = (z0 * HH + y) * WW + x;

    float dzs[2], dhs[2], dws[2];
    #pragma unroll
    for (int j = 0; j < 2; ++j) {
        dzs[j] = ddf[p0 + j * PL];
        dhs[j] = ddf[S + p0 + j * PL];
        dws[j] = ddf[2 * S + p0 + j * PL];
    }

    #pragma unroll
    for (int j = 0; j < 2; ++j) {
        int z = z0 + j;
        int p = p0 + j * PL;
        float cd = fadd((float)z, dzs[j]);
        float ch = fadd((float)y, dhs[j]);
        float cw = fadd((float)x, dws[j]);

        float d0 = floorf(cd), h0 = floorf(ch), w0 = floorf(cw);
        float fd = fsub(cd, d0), fh = fsub(ch, h0), fw = fsub(cw, w0);
        float gd = fsub(1.0f, fd), gh = fsub(1.0f, fh), gw = fsub(1.0f, fw);
        int d0i = (int)d0, h0i = (int)h0, w0i = (int)w0;
        float acc = 0.0f;
        #pragma unroll
        for (int dd = 0; dd < 2; ++dd) {
            #pragma unroll
            for (int dh = 0; dh < 2; ++dh) {
                #pragma unroll
                for (int dw = 0; dw < 2; ++dw) {
                    int di = d0i + dd, hi = h0i + dh, wi = w0i + dw;
                    bool valid = (di >= 0) & (di < DD) & (hi >= 0) & (hi < HH)
                               & (wi >= 0) & (wi < WW);
                    float wgt = fmul(fmul(dd ? fd : gd, dh ? fh : gh), dw ? fw : gw);
                    wgt = valid ? wgt : 0.0f;
                    int dc = min(max(di, 0), DD - 1);
                    int hc = min(max(hi, 0), HH - 1);
                    int wc = min(max(wi, 0), WW - 1);
                    int q = (dc * HH + hc) * WW + wc;
                    acc = fadd(acc, fmul(image[q], wgt));
                }
            }
        }
        out[p] = acc;

        // nearest labels (round half to even, matches jnp.round)
        int di = (int)rintf(cd), hi = (int)rintf(ch), wi = (int)rintf(cw);
        bool valid = (di >= 0) & (di < DD) & (hi >= 0) & (hi < HH)
                   & (wi >= 0) & (wi < WW);
        int dc = min(max(di, 0), DD - 1);
        int hc = min(max(hi, 0), HH - 1);
        int wc = min(max(wi, 0), WW - 1);
        int q = (dc * HH + hc) * WW + wc;
        out[S + p]     = valid ? (float)cav[q] : 0.0f;
        out[2 * S + p] = valid ? (float)cor[q] : 0.0f;
    }
}

extern "C" void kernel_launch(void* const* d_in, const int* in_sizes, int n_in,
                              void* d_out, int out_size, void* d_ws, size_t ws_size,
                              hipStream_t stream) {
    const float* dvf0   = (const float*)d_in[0];
    const float* dvf1   = (const float*)d_in[1];
    const float* image  = (const float*)d_in[2];
    const int*   cav    = (const int*)d_in[3];
    const int*   cor    = (const int*)d_in[4];
    const float* w      = (const float*)d_in[5];

    float* out  = (float*)d_out;
    float* bufA = out;                    // scratch now; img/cav/cor at the end
    float* bufB = out + (size_t)3 * S;    // final planar ddf lives here

    init_kernel<<<12000, 256, 0, stream>>>(dvf0, dvf1, w, bufA);
    warp_step<<<4000, 256, 0, stream>>>(bufA, bufB);   // s1
    warp_step<<<4000, 256, 0, stream>>>(bufB, bufA);   // s2
    warp_step<<<4000, 256, 0, stream>>>(bufA, bufB);   // s3
    warp_step<<<4000, 256, 0, stream>>>(bufB, bufA);   // s4
    warp_step<<<4000, 256, 0, stream>>>(bufA, bufB);   // s5 -> final ddf in bufB
    final_kernel<<<8000, 256, 0, stream>>>(bufB, image, cav, cor, bufA);
}

// Round 5
// 412.536 us; speedup vs baseline: 1.4639x; 1.4639x over previous
//
#include <hip/hip_runtime.h>

#define DD 160
#define HH 160
#define WW 160
#define PL (HH*WW)       // one z-plane = 25600 voxels
#define S (DD*PL)        // 4,096,000 voxels

__device__ __forceinline__ float fmul(float a, float b){ return __fmul_rn(a,b); }
__device__ __forceinline__ float fadd(float a, float b){ return __fadd_rn(a,b); }
__device__ __forceinline__ float fsub(float a, float b){ return __fsub_rn(a,b); }

// ddf0 = (dvf0*(1-w) + dvf1*w) / 32, planar in -> INTERLEAVED out (xyz per voxel)
__global__ __launch_bounds__(256) void init_kernel(const float* __restrict__ dvf0,
                                                   const float* __restrict__ dvf1,
                                                   const float* __restrict__ wp,
                                                   float* __restrict__ outi) {
    int p = (blockIdx.x * 256 + threadIdx.x) * 4;   // 4000 blocks cover S exactly
    float w = wp[0];
    float onew = fsub(1.0f, w);
    float a0[4], a1[4], a2[4], b0[4], b1[4], b2[4];
    *(float4*)a0 = *(const float4*)(dvf0 + p);
    *(float4*)a1 = *(const float4*)(dvf0 + S + p);
    *(float4*)a2 = *(const float4*)(dvf0 + 2 * S + p);
    *(float4*)b0 = *(const float4*)(dvf1 + p);
    *(float4*)b1 = *(const float4*)(dvf1 + S + p);
    *(float4*)b2 = *(const float4*)(dvf1 + 2 * S + p);
    float o[12];
    #pragma unroll
    for (int j = 0; j < 4; ++j) {
        o[3*j]   = fmul(fadd(fmul(a0[j], onew), fmul(b0[j], w)), 0.03125f);
        o[3*j+1] = fmul(fadd(fmul(a1[j], onew), fmul(b1[j], w)), 0.03125f);
        o[3*j+2] = fmul(fadd(fmul(a2[j], onew), fmul(b2[j], w)), 0.03125f);
    }
    float* dst = outi + (size_t)3 * p;
    *(float4*)(dst)     = *(float4*)(o);
    *(float4*)(dst + 4) = *(float4*)(o + 4);
    *(float4*)(dst + 8) = *(float4*)(o + 8);
}

// out = in + trilinear_warp(in, in). INTERLEAVED input (one 12B tap per position,
// 3 channels share cache lines); compact 32x2 wave footprint; 2 voxels/thread (z).
// Grid: 5(x) * 20(y) * 80(z-pairs) = 8000 blocks; swizzle -> 20-plane slab per XCD.
template<bool PLANAR>
__global__ __launch_bounds__(256) void warp_step(const float* __restrict__ in,
                                                 float* __restrict__ out) {
    int b  = (blockIdx.x & 7) * 1000 + (blockIdx.x >> 3);
    int ix = b % 5;
    int r  = b / 5;
    int iy = r % 20;
    int iz = r / 20;                 // 0..79
    int lane = threadIdx.x & 63, wid = threadIdx.x >> 6;
    int x  = (ix << 5) | (lane & 31);
    int y  = (iy << 3) | (wid << 1) | (lane >> 5);
    int z0 = iz << 1;
    int p0 = (z0 * HH + y) * WW + x;

    // center loads for both voxels (12B contiguous per lane)
    float ctr[2][3];
    #pragma unroll
    for (int j = 0; j < 2; ++j) {
        const float* src = in + (size_t)3 * (p0 + j * PL);
        ctr[j][0] = src[0]; ctr[j][1] = src[1]; ctr[j][2] = src[2];
    }

    #pragma unroll
    for (int j = 0; j < 2; ++j) {
        int z = z0 + j;
        int p = p0 + j * PL;
        float vd = ctr[j][0], vh = ctr[j][1], vw = ctr[j][2];
        float cd = fadd((float)z, vd);
        float ch = fadd((float)y, vh);
        float cw = fadd((float)x, vw);

        float d0 = floorf(cd), h0 = floorf(ch), w0 = floorf(cw);
        float fd = fsub(cd, d0), fh = fsub(ch, h0), fw = fsub(cw, w0);
        float gd = fsub(1.0f, fd), gh = fsub(1.0f, fh), gw = fsub(1.0f, fw);
        int d0i = (int)d0, h0i = (int)h0, w0i = (int)w0;

        // phase 1: addresses + weights for all 8 taps
        int   qa[8];
        float wt[8];
        #pragma unroll
        for (int t = 0; t < 8; ++t) {
            int dd = t >> 2, dh = (t >> 1) & 1, dw = t & 1;
            int di = d0i + dd, hi = h0i + dh, wi = w0i + dw;
            bool valid = (di >= 0) & (di < DD) & (hi >= 0) & (hi < HH)
                       & (wi >= 0) & (wi < WW);
            float wgt = fmul(fmul(dd ? fd : gd, dh ? fh : gh), dw ? fw : gw);
            wt[t] = valid ? wgt : 0.0f;     // 0*v == ref's v*0 (values finite)
            int dc = min(max(di, 0), DD - 1);
            int hc = min(max(hi, 0), HH - 1);
            int wc = min(max(wi, 0), WW - 1);
            qa[t] = 3 * ((dc * HH + hc) * WW + wc);
        }
        // phase 2: issue all 8 tap loads (12B each) -> 8-deep MLP
        float g[8][3];
        #pragma unroll
        for (int t = 0; t < 8; ++t) {
            g[t][0] = in[qa[t]];
            g[t][1] = in[qa[t] + 1];
            g[t][2] = in[qa[t] + 2];
        }
        // phase 3: accumulate in reference tap order
        float acc0 = 0.0f, acc1 = 0.0f, acc2 = 0.0f;
        #pragma unroll
        for (int t = 0; t < 8; ++t) {
            acc0 = fadd(acc0, fmul(g[t][0], wt[t]));
            acc1 = fadd(acc1, fmul(g[t][1], wt[t]));
            acc2 = fadd(acc2, fmul(g[t][2], wt[t]));
        }
        float r0 = fadd(vd, acc0);
        float r1 = fadd(vh, acc1);
        float r2 = fadd(vw, acc2);

        if (PLANAR) {
            out[p] = r0; out[S + p] = r1; out[2 * S + p] = r2;
        } else {
            float* dst = out + (size_t)3 * p;
            dst[0] = r0; dst[1] = r1; dst[2] = r2;
        }
    }
}

// img trilinear + cav/cor nearest warp with final (planar) ddf. 2 voxels/thread (z).
// Grid: 5 * 20 * 80 = 8000 blocks; same slab swizzle (20 planes per XCD).
__global__ __launch_bounds__(256) void final_kernel(const float* __restrict__ ddf,
                                                    const float* __restrict__ image,
                                                    const int* __restrict__ cav,
                                                    const int* __restrict__ cor,
                                                    float* __restrict__ out) {
    int b  = (blockIdx.x & 7) * 1000 + (blockIdx.x >> 3);
    int ix = b % 5;
    int r  = b / 5;
    int iy = r % 20;
    int iz = r / 20;                 // 0..79
    int lane = threadIdx.x & 63, wid = threadIdx.x >> 6;
    int x  = (ix << 5) | (lane & 31);
    int y  = (iy << 3) | (wid << 1) | (lane >> 5);
    int z0 = iz << 1;
    int p0 = (z0 * HH + y) * WW + x;

    float dzs[2], dhs[2], dws[2];
    #pragma unroll
    for (int j = 0; j < 2; ++j) {
        dzs[j] = ddf[p0 + j * PL];
        dhs[j] = ddf[S + p0 + j * PL];
        dws[j] = ddf[2 * S + p0 + j * PL];
    }

    #pragma unroll
    for (int j = 0; j < 2; ++j) {
        int z = z0 + j;
        int p = p0 + j * PL;
        float cd = fadd((float)z, dzs[j]);
        float ch = fadd((float)y, dhs[j]);
        float cw = fadd((float)x, dws[j]);

        float d0 = floorf(cd), h0 = floorf(ch), w0 = floorf(cw);
        float fd = fsub(cd, d0), fh = fsub(ch, h0), fw = fsub(cw, w0);
        float gd = fsub(1.0f, fd), gh = fsub(1.0f, fh), gw = fsub(1.0f, fw);
        int d0i = (int)d0, h0i = (int)h0, w0i = (int)w0;

        int   qa[8];
        float wt[8];
        #pragma unroll
        for (int t = 0; t < 8; ++t) {
            int dd = t >> 2, dh = (t >> 1) & 1, dw = t & 1;
            int di = d0i + dd, hi = h0i + dh, wi = w0i + dw;
            bool valid = (di >= 0) & (di < DD) & (hi >= 0) & (hi < HH)
                       & (wi >= 0) & (wi < WW);
            float wgt = fmul(fmul(dd ? fd : gd, dh ? fh : gh), dw ? fw : gw);
            wt[t] = valid ? wgt : 0.0f;
            int dc = min(max(di, 0), DD - 1);
            int hc = min(max(hi, 0), HH - 1);
            int wc = min(max(wi, 0), WW - 1);
            qa[t] = (dc * HH + hc) * WW + wc;
        }
        float g[8];
        #pragma unroll
        for (int t = 0; t < 8; ++t) g[t] = image[qa[t]];
        float acc = 0.0f;
        #pragma unroll
        for (int t = 0; t < 8; ++t) acc = fadd(acc, fmul(g[t], wt[t]));
        out[p] = acc;

        // nearest labels (round half to even, matches jnp.round)
        int di = (int)rintf(cd), hi = (int)rintf(ch), wi = (int)rintf(cw);
        bool valid = (di >= 0) & (di < DD) & (hi >= 0) & (hi < HH)
                   & (wi >= 0) & (wi < WW);
        int dc = min(max(di, 0), DD - 1);
        int hc = min(max(hi, 0), HH - 1);
        int wc = min(max(wi, 0), WW - 1);
        int q = (dc * HH + hc) * WW + wc;
        out[S + p]     = valid ? (float)cav[q] : 0.0f;
        out[2 * S + p] = valid ? (float)cor[q] : 0.0f;
    }
}

extern "C" void kernel_launch(void* const* d_in, const int* in_sizes, int n_in,
                              void* d_out, int out_size, void* d_ws, size_t ws_size,
                              hipStream_t stream) {
    const float* dvf0   = (const float*)d_in[0];
    const float* dvf1   = (const float*)d_in[1];
    const float* image  = (const float*)d_in[2];
    const int*   cav    = (const int*)d_in[3];
    const int*   cor    = (const int*)d_in[4];
    const float* w      = (const float*)d_in[5];

    float* out  = (float*)d_out;
    float* bufA = out;                    // interleaved scratch; img/cav/cor at the end
    float* bufB = out + (size_t)3 * S;    // interleaved scratch; final planar ddf

    init_kernel<<<4000, 256, 0, stream>>>(dvf0, dvf1, w, bufA);
    warp_step<false><<<8000, 256, 0, stream>>>(bufA, bufB);   // s1
    warp_step<false><<<8000, 256, 0, stream>>>(bufB, bufA);   // s2
    warp_step<false><<<8000, 256, 0, stream>>>(bufA, bufB);   // s3
    warp_step<false><<<8000, 256, 0, stream>>>(bufB, bufA);   // s4
    warp_step<true ><<<8000, 256, 0, stream>>>(bufA, bufB);   // s5 -> planar ddf in bufB
    final_kernel<<<8000, 256, 0, stream>>>(bufB, image, cav, cor, bufA);
}